// Round 6
// baseline (323.803 us; speedup 1.0000x reference)
//
#include <hip/hip_runtime.h>
#include <hip/hip_bf16.h>

// GATNet 2-layer GAT, N=50000, E=800000 (+N self loops). f32 in/out, bf16 MFMA
// internally. Round-6: 2 waves per node in agg0/agg1 (edge-split + LDS combine)
// to halve serial-chain latency and degree imbalance; k_prep+k_zero merged.

typedef __attribute__((ext_vector_type(8))) short bf8_t;   // 8 x bf16 (4 VGPRs)
typedef __attribute__((ext_vector_type(4))) float f4_t;

__device__ inline short f2bf(float f) {
    return (short)__builtin_bit_cast(unsigned short, __float2bfloat16(f));
}
__device__ inline float blo(unsigned int p) { return __uint_as_float(p << 16); }
__device__ inline float bhi(unsigned int p) { return __uint_as_float(p & 0xffff0000u); }
__device__ inline float lrexp(float e) {
    e = (e > 0.f) ? e : 0.2f * e;          // leaky_relu(0.2); |e|<~12 -> exp safe
    return __expf(e);
}

// ---------------- init: zero counters + f32->bf16 weight prep ----------------
__global__ void k_init(const float* __restrict__ W0, const float* __restrict__ lW0,
                       const float* __restrict__ W1, const float* __restrict__ lW1,
                       short* __restrict__ Wc0, short* __restrict__ lWc0,
                       short* __restrict__ Wc1, short* __restrict__ lWc1,
                       int* __restrict__ cnt, int N) {
    int i = blockIdx.x * blockDim.x + threadIdx.x;
    if (i < N) cnt[i] = 0;
    if (i < 16384)       Wc0[i]          = f2bf(W0[i]);
    else if (i < 32768)  lWc0[i - 16384] = f2bf(lW0[i - 16384]);
    else if (i < 36864)  Wc1[i - 32768]  = f2bf(W1[i - 32768]);
    else if (i < 40960)  lWc1[i - 36864] = f2bf(lW1[i - 36864]);
}

// ---------------- CSR build ----------------

__global__ void k_count(const int* __restrict__ ei, int* __restrict__ deg, int E, int N) {
    int e = blockIdx.x * blockDim.x + threadIdx.x;
    if (e >= E + N) return;
    int dst = (e < E) ? ei[E + e] : (e - E);   // self-loops appended
    atomicAdd(&deg[dst], 1);
}

__global__ __launch_bounds__(1024) void k_scan1(const int* __restrict__ deg,
                                                int* __restrict__ rowstart,
                                                int* __restrict__ bsum, int n) {
    __shared__ int buf[1024];
    int tid = threadIdx.x, i = blockIdx.x * 1024 + tid;
    int v = (i < n) ? deg[i] : 0;
    buf[tid] = v;
    __syncthreads();
    for (int off = 1; off < 1024; off <<= 1) {
        int t = (tid >= off) ? buf[tid - off] : 0;
        __syncthreads();
        buf[tid] += t;
        __syncthreads();
    }
    if (i < n) rowstart[i] = buf[tid] - v;     // local exclusive
    if (tid == 1023) bsum[blockIdx.x] = buf[1023];
}

__global__ void k_scan2(const int* __restrict__ bsum, int* __restrict__ bcar,
                        int* __restrict__ rowstart, int nb, int n) {
    int lane = threadIdx.x;
    int v = (lane < nb) ? bsum[lane] : 0;
    int s = v;
    #pragma unroll
    for (int off = 1; off < 64; off <<= 1) {
        int t = __shfl_up(s, off);
        if (lane >= off) s += t;
    }
    if (lane < nb) bcar[lane] = s - v;
    if (lane == 63) rowstart[n] = s;
}

__global__ __launch_bounds__(1024) void k_scan3(int* __restrict__ rowstart,
                                                const int* __restrict__ bcar,
                                                int* __restrict__ cur, int n) {
    int i = blockIdx.x * 1024 + threadIdx.x;
    if (i < n) {
        int r = rowstart[i] + bcar[blockIdx.x];
        rowstart[i] = r;
        cur[i] = r;
    }
}

__global__ void k_fill(const int* __restrict__ ei, int* __restrict__ cur,
                       unsigned short* __restrict__ esrc, int E, int N) {
    int e = blockIdx.x * blockDim.x + threadIdx.x;
    if (e >= E + N) return;
    int src, dst;
    if (e < E) { src = ei[e]; dst = ei[E + e]; }
    else       { src = e - E; dst = e - E; }
    int pos = atomicAdd(&cur[dst], 1);
    esrc[pos] = (unsigned short)src;           // N < 65536
}

// ---------------- GEMM0 + fused att0 ----------------
// A-frag: lane holds A[m=lane&15][k=(lane>>4)*8+j]; B-frag: B[k][n=lane&15]
// C/D  : col=lane&15, row=(lane>>4)*4+reg  (m89-verified)

__global__ __launch_bounds__(256) void k_gemm0(
    const float* __restrict__ x,
    const short* __restrict__ Wc0, const short* __restrict__ lWc0,
    const float* __restrict__ as0, const float* __restrict__ ad0,
    __hip_bfloat16* __restrict__ h0, __hip_bfloat16* __restrict__ skipb,
    float* __restrict__ a0s, float* __restrict__ a0d, int N) {
    int wv = threadIdx.x >> 6, lane = threadIdx.x & 63;
    int rowbase = blockIdx.x * 64 + wv * 16;
    int m = lane & 15, q = lane >> 4;
    int arow = rowbase + m; if (arow >= N) arow = N - 1;
    bf8_t a[4];
    #pragma unroll
    for (int kb = 0; kb < 4; kb++) {
        const float4* px = (const float4*)(x + (size_t)arow * 128 + kb * 32 + q * 8);
        float4 lo = px[0], hi = px[1];
        bf8_t f;
        f[0] = f2bf(lo.x); f[1] = f2bf(lo.y); f[2] = f2bf(lo.z); f[3] = f2bf(lo.w);
        f[4] = f2bf(hi.x); f[5] = f2bf(hi.y); f[6] = f2bf(hi.z); f[7] = f2bf(hi.w);
        a[kb] = f;
    }
    float sacc[4][4], dacc[4][4];
    #pragma unroll
    for (int h = 0; h < 4; h++)
        #pragma unroll
        for (int r = 0; r < 4; r++) { sacc[h][r] = 0.f; dacc[h][r] = 0.f; }

    for (int ct = 0; ct < 16; ct++) {
        const short* Wp = (ct < 8) ? Wc0 : lWc0;
        int cb = (ct & 7) * 16;
        f4_t acc = {0.f, 0.f, 0.f, 0.f};
        #pragma unroll
        for (int kb = 0; kb < 4; kb++) {
            bf8_t b = *(const bf8_t*)(Wp + (size_t)(cb + m) * 128 + kb * 32 + q * 8);
            acc = __builtin_amdgcn_mfma_f32_16x16x32_bf16(a[kb], b, acc, 0, 0, 0);
        }
        if (ct < 8) {
            int hd = ct >> 1;
            float ws = as0[cb + m], wd = ad0[cb + m];
            #pragma unroll
            for (int r = 0; r < 4; r++) {
                sacc[hd][r] += acc[r] * ws;
                dacc[hd][r] += acc[r] * wd;
            }
        }
        #pragma unroll
        for (int r = 0; r < 4; r++) {
            int row = rowbase + q * 4 + r;
            if (row < N) {
                int col = cb + m;
                if (ct < 8) h0[(size_t)row * 128 + col]    = __float2bfloat16(acc[r]);
                else        skipb[(size_t)row * 128 + col] = __float2bfloat16(acc[r]);
            }
        }
    }
    #pragma unroll
    for (int h = 0; h < 4; h++)
        #pragma unroll
        for (int r = 0; r < 4; r++) {
            float s = sacc[h][r], d = dacc[h][r];
            #pragma unroll
            for (int off = 1; off < 16; off <<= 1) {
                s += __shfl_xor(s, off);
                d += __shfl_xor(d, off);
            }
            sacc[h][r] = s; dacc[h][r] = d;
        }
    if (m < 4) {
        #pragma unroll
        for (int r = 0; r < 4; r++) {
            int row = rowbase + q * 4 + r;
            if (row < N) {
                float sv = (m == 0) ? sacc[0][r] : (m == 1) ? sacc[1][r]
                         : (m == 2) ? sacc[2][r] : sacc[3][r];
                float dv = (m == 0) ? dacc[0][r] : (m == 1) ? dacc[1][r]
                         : (m == 2) ? dacc[2][r] : dacc[3][r];
                a0s[row * 4 + m] = sv;
                a0d[row * 4 + m] = dv;
            }
        }
    }
}

// ---------------- GEMM1 + fused att1 ----------------

__global__ __launch_bounds__(256) void k_gemm1(
    const __hip_bfloat16* __restrict__ hin,
    const short* __restrict__ Wc1, const short* __restrict__ lWc1,
    const float* __restrict__ as1, const float* __restrict__ ad1,
    __hip_bfloat16* __restrict__ h1, float* __restrict__ skipb /* = d_out */,
    float* __restrict__ a1s, float* __restrict__ a1d, int N) {
    int wv = threadIdx.x >> 6, lane = threadIdx.x & 63;
    int rowbase = blockIdx.x * 64 + wv * 16;
    int m = lane & 15, q = lane >> 4;
    int arow = rowbase + m; if (arow >= N) arow = N - 1;
    const short* xs = (const short*)hin;
    bf8_t a[4];
    #pragma unroll
    for (int kb = 0; kb < 4; kb++)
        a[kb] = *(const bf8_t*)(xs + (size_t)arow * 128 + kb * 32 + q * 8);
    float sacc[4], dacc[4];
    #pragma unroll
    for (int r = 0; r < 4; r++) { sacc[r] = 0.f; dacc[r] = 0.f; }
    #pragma unroll
    for (int ct = 0; ct < 4; ct++) {
        const short* Wp = (ct < 2) ? Wc1 : lWc1;
        int cb = (ct & 1) * 16;
        f4_t acc = {0.f, 0.f, 0.f, 0.f};
        #pragma unroll
        for (int kb = 0; kb < 4; kb++) {
            bf8_t b = *(const bf8_t*)(Wp + (size_t)(cb + m) * 128 + kb * 32 + q * 8);
            acc = __builtin_amdgcn_mfma_f32_16x16x32_bf16(a[kb], b, acc, 0, 0, 0);
        }
        if (ct < 2) {
            float ws = as1[cb + m], wd = ad1[cb + m];
            #pragma unroll
            for (int r = 0; r < 4; r++) {
                sacc[r] += acc[r] * ws;
                dacc[r] += acc[r] * wd;
            }
        }
        #pragma unroll
        for (int r = 0; r < 4; r++) {
            int row = rowbase + q * 4 + r;
            if (row < N) {
                size_t idx = (size_t)row * 32 + cb + m;
                if (ct < 2) h1[idx] = __float2bfloat16(acc[r]);
                else        skipb[idx] = acc[r];
            }
        }
    }
    #pragma unroll
    for (int r = 0; r < 4; r++) {
        float s = sacc[r], d = dacc[r];
        #pragma unroll
        for (int off = 1; off < 16; off <<= 1) {
            s += __shfl_xor(s, off);
            d += __shfl_xor(d, off);
        }
        if (m == 0) {
            int row = rowbase + q * 4 + r;
            if (row < N) { a1s[row] = s; a1d[row] = d; }
        }
    }
}

// ---------------- aggregation: 2 waves per node ----------------

// block = 256 threads = 4 waves = 2 nodes x 2 waves. Wave pair splits the edge
// list even/odd; partials combined in LDS. lane handles channels 2l,2l+1.
__global__ __launch_bounds__(256) void k_agg0(
    const int* __restrict__ rowstart, const unsigned short* __restrict__ esrc,
    const unsigned int* __restrict__ h0u,              // h0 packed bf16x2
    const float* __restrict__ a0s, const float* __restrict__ a0d,
    const float* __restrict__ bias0, const float* __restrict__ linb0,
    unsigned int* __restrict__ h1in_u,                 // in: skip0 bf16, out: ELU
    int n) {
    __shared__ float l0[2][64], l1[2][64], ld[2][64];
    int slot = threadIdx.x >> 7;               // node within block (0,1)
    int half = (threadIdx.x >> 6) & 1;         // edge-stream (0,1)
    int lane = threadIdx.x & 63;
    int node = blockIdx.x * 2 + slot;
    bool valid = node < n;
    int hd = lane >> 4;
    float den = 0.f, acc0 = 0.f, acc1 = 0.f;
    if (valid) {
        float ad = a0d[node * 4 + hd];
        int s0 = rowstart[node], s1 = rowstart[node + 1];
        int i = s0 + half;
        for (; i + 6 < s1; i += 8) {           // 4 edges per wave per iter
            int s[4]; float e[4]; unsigned int p[4];
            #pragma unroll
            for (int j = 0; j < 4; j++) s[j] = esrc[i + 2 * j];
            #pragma unroll
            for (int j = 0; j < 4; j++) e[j] = a0s[s[j] * 4 + hd] + ad;
            #pragma unroll
            for (int j = 0; j < 4; j++) p[j] = h0u[(size_t)s[j] * 64 + lane];
            #pragma unroll
            for (int j = 0; j < 4; j++) {
                float wgt = lrexp(e[j]);
                den += wgt; acc0 += wgt * blo(p[j]); acc1 += wgt * bhi(p[j]);
            }
        }
        for (; i < s1; i += 2) {
            int s = esrc[i];
            float wgt = lrexp(a0s[s * 4 + hd] + ad);
            unsigned int p = h0u[(size_t)s * 64 + lane];
            den += wgt; acc0 += wgt * blo(p); acc1 += wgt * bhi(p);
        }
    }
    if (half == 1) { l0[slot][lane] = acc0; l1[slot][lane] = acc1; ld[slot][lane] = den; }
    __syncthreads();
    if (valid && half == 0) {
        acc0 += l0[slot][lane]; acc1 += l1[slot][lane]; den += ld[slot][lane];
        float inv = 1.0f / (den + 1e-16f);
        int c0 = lane * 2;
        unsigned int sp = h1in_u[(size_t)node * 64 + lane];   // skip0 (bf16 pair)
        float o0 = acc0 * inv + blo(sp) + bias0[c0]     + linb0[c0];
        float o1 = acc1 * inv + bhi(sp) + bias0[c0 + 1] + linb0[c0 + 1];
        o0 = (o0 > 0.f) ? o0 : (__expf(o0) - 1.f);  // ELU
        o1 = (o1 > 0.f) ? o1 : (__expf(o1) - 1.f);
        unsigned int r0 = (unsigned int)(unsigned short)f2bf(o0);
        unsigned int r1 = (unsigned int)(unsigned short)f2bf(o1);
        h1in_u[(size_t)node * 64 + lane] = r0 | (r1 << 16);
    }
}

// 2 waves per node; each wave's 32-lane halves split further -> 4 edge streams.
// channel c = lane&31. d_out (f32) holds skip1 on entry, final on exit.
__global__ __launch_bounds__(256) void k_agg1(
    const int* __restrict__ rowstart, const unsigned short* __restrict__ esrc,
    const __hip_bfloat16* __restrict__ h1,
    const float* __restrict__ a1s, const float* __restrict__ a1d,
    const float* __restrict__ bias1, const float* __restrict__ linb1,
    float* __restrict__ out, int n) {
    __shared__ float la[2][32], ldn[2][32];
    int slot = threadIdx.x >> 7;
    int half = (threadIdx.x >> 6) & 1;
    int lane = threadIdx.x & 63;
    int node = blockIdx.x * 2 + slot;
    bool valid = node < n;
    int c = lane & 31, sub = lane >> 5;
    const unsigned short* h1u = (const unsigned short*)h1;
    float den = 0.f, acc = 0.f;
    if (valid) {
        float ad = a1d[node];
        int s0 = rowstart[node], s1 = rowstart[node + 1];
        int i = s0 + half * 2 + sub;           // streams 0..3, stride 4
        for (; i + 4 < s1; i += 8) {           // 2 edges per stream per iter
            int sA = esrc[i], sB = esrc[i + 4];
            float eA = a1s[sA] + ad, eB = a1s[sB] + ad;
            unsigned int hA = h1u[(size_t)sA * 32 + c];
            unsigned int hB = h1u[(size_t)sB * 32 + c];
            float wA = lrexp(eA), wB = lrexp(eB);
            den += wA + wB;
            acc += wA * __uint_as_float(hA << 16) + wB * __uint_as_float(hB << 16);
        }
        for (; i < s1; i += 4) {
            int s = esrc[i];
            float wgt = lrexp(a1s[s] + ad);
            den += wgt;
            acc += wgt * __uint_as_float((unsigned int)h1u[(size_t)s * 32 + c] << 16);
        }
    }
    acc += __shfl_xor(acc, 32);
    den += __shfl_xor(den, 32);
    if (half == 1 && lane < 32) { la[slot][c] = acc; ldn[slot][c] = den; }
    __syncthreads();
    if (valid && half == 0 && lane < 32) {
        acc += la[slot][c]; den += ldn[slot][c];
        size_t idx = (size_t)node * 32 + c;
        out[idx] = acc / (den + 1e-16f) + out[idx] + bias1[c] + linb1[c];
    }
}

// ---------------- launch ----------------

extern "C" void kernel_launch(void* const* d_in, const int* in_sizes, int n_in,
                              void* d_out, int out_size, void* d_ws, size_t ws_size,
                              hipStream_t stream) {
    const float* x   = (const float*)d_in[0];
    const int*   ei  = (const int*)d_in[1];
    const float* W0  = (const float*)d_in[2];
    const float* as0 = (const float*)d_in[3];
    const float* ad0 = (const float*)d_in[4];
    const float* b0  = (const float*)d_in[5];
    const float* lW0 = (const float*)d_in[6];
    const float* lb0 = (const float*)d_in[7];
    const float* W1  = (const float*)d_in[8];
    const float* as1 = (const float*)d_in[9];
    const float* ad1 = (const float*)d_in[10];
    const float* b1  = (const float*)d_in[11];
    const float* lW1 = (const float*)d_in[12];
    const float* lb1 = (const float*)d_in[13];
    float* out = (float*)d_out;

    const int N = in_sizes[0] / 128;
    const int E = in_sizes[1] / 2;
    const int T = E + N;
    const int NB = (N + 1023) / 1024;

    // workspace carve-up (256B aligned), ~29.5 MB
    char* w = (char*)d_ws;
    auto alloc = [&](size_t bytes) -> char* {
        char* p = w; w += (bytes + 255) / 256 * 256; return p;
    };
    int* rowstart  = (int*)alloc((size_t)(N + 1) * 4);
    int* cnt       = (int*)alloc((size_t)N * 4);          // deg, then fill-cursor
    int* bsum      = (int*)alloc(64 * 4);
    int* bcar      = (int*)alloc(64 * 4);
    unsigned short* esrc = (unsigned short*)alloc((size_t)T * 2);
    float* aS      = (float*)alloc((size_t)N * 4 * 4);    // layer0 [N,4]; layer1 [N]
    float* aD      = (float*)alloc((size_t)N * 4 * 4);
    __hip_bfloat16* hbuf = (__hip_bfloat16*)alloc((size_t)N * 128 * 2); // h0 / h1
    __hip_bfloat16* h1in = (__hip_bfloat16*)alloc((size_t)N * 128 * 2); // skip0 -> ELU
    short* Wc0  = (short*)alloc(16384 * 2);
    short* lWc0 = (short*)alloc(16384 * 2);
    short* Wc1  = (short*)alloc(4096 * 2);
    short* lWc1 = (short*)alloc(4096 * 2);

    // init (zero counters + weight prep), then CSR build
    k_init<<<(N + 255) / 256, 256, 0, stream>>>(W0, lW0, W1, lW1,
                                                Wc0, lWc0, Wc1, lWc1, cnt, N);
    k_count<<<(T + 255) / 256, 256, 0, stream>>>(ei, cnt, E, N);
    k_scan1<<<NB, 1024, 0, stream>>>(cnt, rowstart, bsum, N);
    k_scan2<<<1, 64, 0, stream>>>(bsum, bcar, rowstart, NB, N);
    k_scan3<<<NB, 1024, 0, stream>>>(rowstart, bcar, cnt, N);
    k_fill<<<(T + 255) / 256, 256, 0, stream>>>(ei, cnt, esrc, E, N);

    // layer 0 (att fused into gemm)
    k_gemm0<<<(N + 63) / 64, 256, 0, stream>>>(x, Wc0, lWc0, as0, ad0,
                                               hbuf, h1in, aS, aD, N);
    k_agg0<<<(N + 1) / 2, 256, 0, stream>>>(rowstart, esrc, (const unsigned int*)hbuf,
                                            aS, aD, b0, lb0, (unsigned int*)h1in, N);
    // layer 1 (h1 reuses hbuf; skip1 lives in d_out f32; att fused)
    k_gemm1<<<(N + 63) / 64, 256, 0, stream>>>(h1in, Wc1, lWc1, as1, ad1,
                                               hbuf, out, aS, aD, N);
    k_agg1<<<(N + 1) / 2, 256, 0, stream>>>(rowstart, esrc, hbuf, aS, aD,
                                            b1, lb1, out, N);
}

// Round 7
// 294.101 us; speedup vs baseline: 1.1010x; 1.1010x over previous
//
#include <hip/hip_runtime.h>
#include <hip/hip_bf16.h>

// GATNet 2-layer GAT, N=50000, E=800000 (+N self loops). f32 in/out, bf16 MFMA
// internally. Round-7: revert 2-wave split (regressed); agg kernels restructured
// to 16-lane edge groups: 4 edges in flight/wave, uint4 row gathers (4x fewer
// VMEM instrs), epilogue shfl_xor combine. bias+linb pre-summed (bc0/bc1).

typedef __attribute__((ext_vector_type(8))) short bf8_t;   // 8 x bf16 (4 VGPRs)
typedef __attribute__((ext_vector_type(4))) float f4_t;

__device__ inline short f2bf(float f) {
    return (short)__builtin_bit_cast(unsigned short, __float2bfloat16(f));
}
__device__ inline float blo(unsigned int p) { return __uint_as_float(p << 16); }
__device__ inline float bhi(unsigned int p) { return __uint_as_float(p & 0xffff0000u); }
__device__ inline float lrexp(float e) {
    e = (e > 0.f) ? e : 0.2f * e;          // leaky_relu(0.2); |e|<~12 -> exp safe
    return __expf(e);
}

// ---- init: zero counters + f32->bf16 weight prep + combined biases ----
__global__ void k_init(const float* __restrict__ W0, const float* __restrict__ lW0,
                       const float* __restrict__ W1, const float* __restrict__ lW1,
                       const float* __restrict__ b0, const float* __restrict__ lb0,
                       const float* __restrict__ b1, const float* __restrict__ lb1,
                       short* __restrict__ Wc0, short* __restrict__ lWc0,
                       short* __restrict__ Wc1, short* __restrict__ lWc1,
                       float* __restrict__ bc0, float* __restrict__ bc1,
                       int* __restrict__ cnt, int N) {
    int i = blockIdx.x * blockDim.x + threadIdx.x;
    if (i < N) cnt[i] = 0;
    if (i < 16384)       Wc0[i]          = f2bf(W0[i]);
    else if (i < 32768)  lWc0[i - 16384] = f2bf(lW0[i - 16384]);
    else if (i < 36864)  Wc1[i - 32768]  = f2bf(W1[i - 32768]);
    else if (i < 40960)  lWc1[i - 36864] = f2bf(lW1[i - 36864]);
    if (i < 128) bc0[i] = b0[i] + lb0[i];
    else if (i < 160) bc1[i - 128] = b1[i - 128] + lb1[i - 128];
}

// ---------------- CSR build ----------------

__global__ void k_count(const int* __restrict__ ei, int* __restrict__ deg, int E, int N) {
    int e = blockIdx.x * blockDim.x + threadIdx.x;
    if (e >= E + N) return;
    int dst = (e < E) ? ei[E + e] : (e - E);   // self-loops appended
    atomicAdd(&deg[dst], 1);
}

__global__ __launch_bounds__(1024) void k_scan1(const int* __restrict__ deg,
                                                int* __restrict__ rowstart,
                                                int* __restrict__ bsum, int n) {
    __shared__ int buf[1024];
    int tid = threadIdx.x, i = blockIdx.x * 1024 + tid;
    int v = (i < n) ? deg[i] : 0;
    buf[tid] = v;
    __syncthreads();
    for (int off = 1; off < 1024; off <<= 1) {
        int t = (tid >= off) ? buf[tid - off] : 0;
        __syncthreads();
        buf[tid] += t;
        __syncthreads();
    }
    if (i < n) rowstart[i] = buf[tid] - v;     // local exclusive
    if (tid == 1023) bsum[blockIdx.x] = buf[1023];
}

__global__ void k_scan2(const int* __restrict__ bsum, int* __restrict__ bcar,
                        int* __restrict__ rowstart, int nb, int n) {
    int lane = threadIdx.x;
    int v = (lane < nb) ? bsum[lane] : 0;
    int s = v;
    #pragma unroll
    for (int off = 1; off < 64; off <<= 1) {
        int t = __shfl_up(s, off);
        if (lane >= off) s += t;
    }
    if (lane < nb) bcar[lane] = s - v;
    if (lane == 63) rowstart[n] = s;
}

__global__ __launch_bounds__(1024) void k_scan3(int* __restrict__ rowstart,
                                                const int* __restrict__ bcar,
                                                int* __restrict__ cur, int n) {
    int i = blockIdx.x * 1024 + threadIdx.x;
    if (i < n) {
        int r = rowstart[i] + bcar[blockIdx.x];
        rowstart[i] = r;
        cur[i] = r;
    }
}

__global__ void k_fill(const int* __restrict__ ei, int* __restrict__ cur,
                       unsigned short* __restrict__ esrc, int E, int N) {
    int e = blockIdx.x * blockDim.x + threadIdx.x;
    if (e >= E + N) return;
    int src, dst;
    if (e < E) { src = ei[e]; dst = ei[E + e]; }
    else       { src = e - E; dst = e - E; }
    int pos = atomicAdd(&cur[dst], 1);
    esrc[pos] = (unsigned short)src;           // N < 65536
}

// ---------------- GEMM0 + fused att0 ----------------
// A-frag: lane holds A[m=lane&15][k=(lane>>4)*8+j]; B-frag: B[k][n=lane&15]
// C/D  : col=lane&15, row=(lane>>4)*4+reg  (m89-verified)

__global__ __launch_bounds__(256) void k_gemm0(
    const float* __restrict__ x,
    const short* __restrict__ Wc0, const short* __restrict__ lWc0,
    const float* __restrict__ as0, const float* __restrict__ ad0,
    __hip_bfloat16* __restrict__ h0, __hip_bfloat16* __restrict__ skipb,
    float* __restrict__ a0s, float* __restrict__ a0d, int N) {
    int wv = threadIdx.x >> 6, lane = threadIdx.x & 63;
    int rowbase = blockIdx.x * 64 + wv * 16;
    int m = lane & 15, q = lane >> 4;
    int arow = rowbase + m; if (arow >= N) arow = N - 1;
    bf8_t a[4];
    #pragma unroll
    for (int kb = 0; kb < 4; kb++) {
        const float4* px = (const float4*)(x + (size_t)arow * 128 + kb * 32 + q * 8);
        float4 lo = px[0], hi = px[1];
        bf8_t f;
        f[0] = f2bf(lo.x); f[1] = f2bf(lo.y); f[2] = f2bf(lo.z); f[3] = f2bf(lo.w);
        f[4] = f2bf(hi.x); f[5] = f2bf(hi.y); f[6] = f2bf(hi.z); f[7] = f2bf(hi.w);
        a[kb] = f;
    }
    float sacc[4][4], dacc[4][4];
    #pragma unroll
    for (int h = 0; h < 4; h++)
        #pragma unroll
        for (int r = 0; r < 4; r++) { sacc[h][r] = 0.f; dacc[h][r] = 0.f; }

    for (int ct = 0; ct < 16; ct++) {
        const short* Wp = (ct < 8) ? Wc0 : lWc0;
        int cb = (ct & 7) * 16;
        f4_t acc = {0.f, 0.f, 0.f, 0.f};
        #pragma unroll
        for (int kb = 0; kb < 4; kb++) {
            bf8_t b = *(const bf8_t*)(Wp + (size_t)(cb + m) * 128 + kb * 32 + q * 8);
            acc = __builtin_amdgcn_mfma_f32_16x16x32_bf16(a[kb], b, acc, 0, 0, 0);
        }
        if (ct < 8) {
            int hd = ct >> 1;
            float ws = as0[cb + m], wd = ad0[cb + m];
            #pragma unroll
            for (int r = 0; r < 4; r++) {
                sacc[hd][r] += acc[r] * ws;
                dacc[hd][r] += acc[r] * wd;
            }
        }
        #pragma unroll
        for (int r = 0; r < 4; r++) {
            int row = rowbase + q * 4 + r;
            if (row < N) {
                int col = cb + m;
                if (ct < 8) h0[(size_t)row * 128 + col]    = __float2bfloat16(acc[r]);
                else        skipb[(size_t)row * 128 + col] = __float2bfloat16(acc[r]);
            }
        }
    }
    #pragma unroll
    for (int h = 0; h < 4; h++)
        #pragma unroll
        for (int r = 0; r < 4; r++) {
            float s = sacc[h][r], d = dacc[h][r];
            #pragma unroll
            for (int off = 1; off < 16; off <<= 1) {
                s += __shfl_xor(s, off);
                d += __shfl_xor(d, off);
            }
            sacc[h][r] = s; dacc[h][r] = d;
        }
    if (m < 4) {
        #pragma unroll
        for (int r = 0; r < 4; r++) {
            int row = rowbase + q * 4 + r;
            if (row < N) {
                float sv = (m == 0) ? sacc[0][r] : (m == 1) ? sacc[1][r]
                         : (m == 2) ? sacc[2][r] : sacc[3][r];
                float dv = (m == 0) ? dacc[0][r] : (m == 1) ? dacc[1][r]
                         : (m == 2) ? dacc[2][r] : dacc[3][r];
                a0s[row * 4 + m] = sv;
                a0d[row * 4 + m] = dv;
            }
        }
    }
}

// ---------------- GEMM1 + fused att1 ----------------

__global__ __launch_bounds__(256) void k_gemm1(
    const __hip_bfloat16* __restrict__ hin,
    const short* __restrict__ Wc1, const short* __restrict__ lWc1,
    const float* __restrict__ as1, const float* __restrict__ ad1,
    __hip_bfloat16* __restrict__ h1, float* __restrict__ skipb /* = d_out */,
    float* __restrict__ a1s, float* __restrict__ a1d, int N) {
    int wv = threadIdx.x >> 6, lane = threadIdx.x & 63;
    int rowbase = blockIdx.x * 64 + wv * 16;
    int m = lane & 15, q = lane >> 4;
    int arow = rowbase + m; if (arow >= N) arow = N - 1;
    const short* xs = (const short*)hin;
    bf8_t a[4];
    #pragma unroll
    for (int kb = 0; kb < 4; kb++)
        a[kb] = *(const bf8_t*)(xs + (size_t)arow * 128 + kb * 32 + q * 8);
    float sacc[4], dacc[4];
    #pragma unroll
    for (int r = 0; r < 4; r++) { sacc[r] = 0.f; dacc[r] = 0.f; }
    #pragma unroll
    for (int ct = 0; ct < 4; ct++) {
        const short* Wp = (ct < 2) ? Wc1 : lWc1;
        int cb = (ct & 1) * 16;
        f4_t acc = {0.f, 0.f, 0.f, 0.f};
        #pragma unroll
        for (int kb = 0; kb < 4; kb++) {
            bf8_t b = *(const bf8_t*)(Wp + (size_t)(cb + m) * 128 + kb * 32 + q * 8);
            acc = __builtin_amdgcn_mfma_f32_16x16x32_bf16(a[kb], b, acc, 0, 0, 0);
        }
        if (ct < 2) {
            float ws = as1[cb + m], wd = ad1[cb + m];
            #pragma unroll
            for (int r = 0; r < 4; r++) {
                sacc[r] += acc[r] * ws;
                dacc[r] += acc[r] * wd;
            }
        }
        #pragma unroll
        for (int r = 0; r < 4; r++) {
            int row = rowbase + q * 4 + r;
            if (row < N) {
                size_t idx = (size_t)row * 32 + cb + m;
                if (ct < 2) h1[idx] = __float2bfloat16(acc[r]);
                else        skipb[idx] = acc[r];
            }
        }
    }
    #pragma unroll
    for (int r = 0; r < 4; r++) {
        float s = sacc[r], d = dacc[r];
        #pragma unroll
        for (int off = 1; off < 16; off <<= 1) {
            s += __shfl_xor(s, off);
            d += __shfl_xor(d, off);
        }
        if (m == 0) {
            int row = rowbase + q * 4 + r;
            if (row < N) { a1s[row] = s; a1d[row] = d; }
        }
    }
}

// ---------------- aggregation: 16-lane edge groups, 1 wave/node ----------------

// lane t of group g covers channels 8t..8t+7 (uint4 gather); group g takes
// edges s0+g, s0+g+4, ... Epilogue: shfl_xor(16,32) combine; group 0 stores.
__global__ __launch_bounds__(256) void k_agg0(
    const int* __restrict__ rowstart, const unsigned short* __restrict__ esrc,
    const unsigned int* __restrict__ h0u,              // row = 64 uints (bf16x2)
    const float* __restrict__ a0s, const float* __restrict__ a0d,
    const float* __restrict__ bc0,                     // bias0+linb0 [128]
    unsigned int* __restrict__ h1in_u,                 // in: skip0 bf16, out: ELU
    int n) {
    int node = (blockIdx.x * 256 + threadIdx.x) >> 6;
    int lane = threadIdx.x & 63;
    if (node >= n) return;
    int g = lane >> 4, t = lane & 15, hd = t >> 2;
    float ad = a0d[node * 4 + hd];
    int s0 = rowstart[node], s1 = rowstart[node + 1];
    float den = 0.f;
    float acc[8];
    #pragma unroll
    for (int k = 0; k < 8; k++) acc[k] = 0.f;
    int i = s0 + g;
    for (; i + 4 < s1; i += 8) {               // 2 edges/group/iter = 8/wave
        int sA = esrc[i], sB = esrc[i + 4];
        float eA = a0s[sA * 4 + hd] + ad;
        float eB = a0s[sB * 4 + hd] + ad;
        uint4 pA = *(const uint4*)(h0u + (size_t)sA * 64 + t * 4);
        uint4 pB = *(const uint4*)(h0u + (size_t)sB * 64 + t * 4);
        float wA = lrexp(eA), wB = lrexp(eB);
        den += wA + wB;
        acc[0] += wA * blo(pA.x) + wB * blo(pB.x);
        acc[1] += wA * bhi(pA.x) + wB * bhi(pB.x);
        acc[2] += wA * blo(pA.y) + wB * blo(pB.y);
        acc[3] += wA * bhi(pA.y) + wB * bhi(pB.y);
        acc[4] += wA * blo(pA.z) + wB * blo(pB.z);
        acc[5] += wA * bhi(pA.z) + wB * bhi(pB.z);
        acc[6] += wA * blo(pA.w) + wB * blo(pB.w);
        acc[7] += wA * bhi(pA.w) + wB * bhi(pB.w);
    }
    for (; i < s1; i += 4) {
        int s = esrc[i];
        float wv = lrexp(a0s[s * 4 + hd] + ad);
        uint4 p = *(const uint4*)(h0u + (size_t)s * 64 + t * 4);
        den += wv;
        acc[0] += wv * blo(p.x); acc[1] += wv * bhi(p.x);
        acc[2] += wv * blo(p.y); acc[3] += wv * bhi(p.y);
        acc[4] += wv * blo(p.z); acc[5] += wv * bhi(p.z);
        acc[6] += wv * blo(p.w); acc[7] += wv * bhi(p.w);
    }
    #pragma unroll
    for (int k = 0; k < 8; k++) {
        acc[k] += __shfl_xor(acc[k], 16);
        acc[k] += __shfl_xor(acc[k], 32);
    }
    den += __shfl_xor(den, 16);
    den += __shfl_xor(den, 32);
    if (g == 0) {
        float inv = 1.0f / (den + 1e-16f);
        uint4 sp = *(const uint4*)(h1in_u + (size_t)node * 64 + t * 4); // skip0
        int c0 = t * 8;
        float o[8];
        o[0] = acc[0] * inv + blo(sp.x) + bc0[c0 + 0];
        o[1] = acc[1] * inv + bhi(sp.x) + bc0[c0 + 1];
        o[2] = acc[2] * inv + blo(sp.y) + bc0[c0 + 2];
        o[3] = acc[3] * inv + bhi(sp.y) + bc0[c0 + 3];
        o[4] = acc[4] * inv + blo(sp.z) + bc0[c0 + 4];
        o[5] = acc[5] * inv + bhi(sp.z) + bc0[c0 + 5];
        o[6] = acc[6] * inv + blo(sp.w) + bc0[c0 + 6];
        o[7] = acc[7] * inv + bhi(sp.w) + bc0[c0 + 7];
        #pragma unroll
        for (int k = 0; k < 8; k++)
            o[k] = (o[k] > 0.f) ? o[k] : (__expf(o[k]) - 1.f);  // ELU
        uint4 res;
        res.x = (unsigned int)(unsigned short)f2bf(o[0]) | ((unsigned int)(unsigned short)f2bf(o[1]) << 16);
        res.y = (unsigned int)(unsigned short)f2bf(o[2]) | ((unsigned int)(unsigned short)f2bf(o[3]) << 16);
        res.z = (unsigned int)(unsigned short)f2bf(o[4]) | ((unsigned int)(unsigned short)f2bf(o[5]) << 16);
        res.w = (unsigned int)(unsigned short)f2bf(o[6]) | ((unsigned int)(unsigned short)f2bf(o[7]) << 16);
        *(uint4*)(h1in_u + (size_t)node * 64 + t * 4) = res;
    }
}

// lane t of group g covers channels 2t,2t+1 (uint gather); group g takes edges
// s0+g, s0+g+4, ... d_out (f32) holds skip1 on entry, final on exit.
__global__ __launch_bounds__(256) void k_agg1(
    const int* __restrict__ rowstart, const unsigned short* __restrict__ esrc,
    const __hip_bfloat16* __restrict__ h1,
    const float* __restrict__ a1s, const float* __restrict__ a1d,
    const float* __restrict__ bc1,                     // bias1+linb1 [32]
    float* __restrict__ out, int n) {
    int node = (blockIdx.x * 256 + threadIdx.x) >> 6;
    int lane = threadIdx.x & 63;
    if (node >= n) return;
    int g = lane >> 4, t = lane & 15;
    float ad = a1d[node];
    int s0 = rowstart[node], s1 = rowstart[node + 1];
    const unsigned int* h1w = (const unsigned int*)h1;  // row = 16 uints
    float den = 0.f, acc0 = 0.f, acc1 = 0.f;
    int i = s0 + g;
    for (; i + 4 < s1; i += 8) {
        int sA = esrc[i], sB = esrc[i + 4];
        float eA = a1s[sA] + ad, eB = a1s[sB] + ad;
        unsigned int pA = h1w[(size_t)sA * 16 + t];
        unsigned int pB = h1w[(size_t)sB * 16 + t];
        float wA = lrexp(eA), wB = lrexp(eB);
        den += wA + wB;
        acc0 += wA * blo(pA) + wB * blo(pB);
        acc1 += wA * bhi(pA) + wB * bhi(pB);
    }
    for (; i < s1; i += 4) {
        int s = esrc[i];
        float wv = lrexp(a1s[s] + ad);
        unsigned int p = h1w[(size_t)s * 16 + t];
        den += wv; acc0 += wv * blo(p); acc1 += wv * bhi(p);
    }
    acc0 += __shfl_xor(acc0, 16); acc0 += __shfl_xor(acc0, 32);
    acc1 += __shfl_xor(acc1, 16); acc1 += __shfl_xor(acc1, 32);
    den  += __shfl_xor(den, 16);  den  += __shfl_xor(den, 32);
    if (g == 0) {
        float inv = 1.0f / (den + 1e-16f);
        int c0 = t * 2;
        size_t idx = (size_t)node * 32 + c0;
        float2 sk = *(const float2*)(out + idx);     // skip1
        float2 r;
        r.x = acc0 * inv + sk.x + bc1[c0];
        r.y = acc1 * inv + sk.y + bc1[c0 + 1];
        *(float2*)(out + idx) = r;
    }
}

// ---------------- launch ----------------

extern "C" void kernel_launch(void* const* d_in, const int* in_sizes, int n_in,
                              void* d_out, int out_size, void* d_ws, size_t ws_size,
                              hipStream_t stream) {
    const float* x   = (const float*)d_in[0];
    const int*   ei  = (const int*)d_in[1];
    const float* W0  = (const float*)d_in[2];
    const float* as0 = (const float*)d_in[3];
    const float* ad0 = (const float*)d_in[4];
    const float* b0  = (const float*)d_in[5];
    const float* lW0 = (const float*)d_in[6];
    const float* lb0 = (const float*)d_in[7];
    const float* W1  = (const float*)d_in[8];
    const float* as1 = (const float*)d_in[9];
    const float* ad1 = (const float*)d_in[10];
    const float* b1  = (const float*)d_in[11];
    const float* lW1 = (const float*)d_in[12];
    const float* lb1 = (const float*)d_in[13];
    float* out = (float*)d_out;

    const int N = in_sizes[0] / 128;
    const int E = in_sizes[1] / 2;
    const int T = E + N;
    const int NB = (N + 1023) / 1024;

    // workspace carve-up (256B aligned), ~29.5 MB
    char* w = (char*)d_ws;
    auto alloc = [&](size_t bytes) -> char* {
        char* p = w; w += (bytes + 255) / 256 * 256; return p;
    };
    int* rowstart  = (int*)alloc((size_t)(N + 1) * 4);
    int* cnt       = (int*)alloc((size_t)N * 4);          // deg, then fill-cursor
    int* bsum      = (int*)alloc(64 * 4);
    int* bcar      = (int*)alloc(64 * 4);
    unsigned short* esrc = (unsigned short*)alloc((size_t)T * 2);
    float* aS      = (float*)alloc((size_t)N * 4 * 4);    // layer0 [N,4]; layer1 [N]
    float* aD      = (float*)alloc((size_t)N * 4 * 4);
    __hip_bfloat16* hbuf = (__hip_bfloat16*)alloc((size_t)N * 128 * 2); // h0 / h1
    __hip_bfloat16* h1in = (__hip_bfloat16*)alloc((size_t)N * 128 * 2); // skip0 -> ELU
    short* Wc0  = (short*)alloc(16384 * 2);
    short* lWc0 = (short*)alloc(16384 * 2);
    short* Wc1  = (short*)alloc(4096 * 2);
    short* lWc1 = (short*)alloc(4096 * 2);
    float* bc0  = (float*)alloc(128 * 4);
    float* bc1  = (float*)alloc(32 * 4);

    // init (zero counters + weight prep + combined biases), then CSR build
    k_init<<<(N + 255) / 256, 256, 0, stream>>>(W0, lW0, W1, lW1, b0, lb0, b1, lb1,
                                                Wc0, lWc0, Wc1, lWc1, bc0, bc1, cnt, N);
    k_count<<<(T + 255) / 256, 256, 0, stream>>>(ei, cnt, E, N);
    k_scan1<<<NB, 1024, 0, stream>>>(cnt, rowstart, bsum, N);
    k_scan2<<<1, 64, 0, stream>>>(bsum, bcar, rowstart, NB, N);
    k_scan3<<<NB, 1024, 0, stream>>>(rowstart, bcar, cnt, N);
    k_fill<<<(T + 255) / 256, 256, 0, stream>>>(ei, cnt, esrc, E, N);

    // layer 0 (att fused into gemm)
    k_gemm0<<<(N + 63) / 64, 256, 0, stream>>>(x, Wc0, lWc0, as0, ad0,
                                               hbuf, h1in, aS, aD, N);
    k_agg0<<<(N + 3) / 4, 256, 0, stream>>>(rowstart, esrc, (const unsigned int*)hbuf,
                                            aS, aD, bc0, (unsigned int*)h1in, N);
    // layer 1 (h1 reuses hbuf; skip1 lives in d_out f32; att fused)
    k_gemm1<<<(N + 63) / 64, 256, 0, stream>>>(h1in, Wc1, lWc1, as1, ad1,
                                               hbuf, out, aS, aD, N);
    k_agg1<<<(N + 3) / 4, 256, 0, stream>>>(rowstart, esrc, hbuf, aS, aD,
                                            bc1, out, N);
}